// Round 1
// baseline (141.739 us; speedup 1.0000x reference)
//
#include <hip/hip_runtime.h>

namespace {

constexpr int B = 4;
constexpr int N = 8192;
constexpr int E = 24576;
constexpr int BN = B * N;
constexpr int CHUNK = 1024;   // m/n chunk staged in LDS per block (16 KB of float4)

// Monotonic float <-> uint mapping (total order matches float compare incl. negatives)
__device__ __forceinline__ unsigned fkey(float f) {
  unsigned b = __float_as_uint(f);
  return b ^ ((b & 0x80000000u) ? 0xFFFFFFFFu : 0x80000000u);
}
__device__ __forceinline__ float funkey(unsigned k) {
  unsigned b = k ^ ((k & 0x80000000u) ? 0x80000000u : 0xFFFFFFFFu);
  return __uint_as_float(b);
}
__device__ __forceinline__ unsigned long long umin64(unsigned long long a, unsigned long long b) {
  return a < b ? a : b;
}

// sums layout (floats): [0]=s1 (sum mins1), [1]=s2 (sum mins2), [2]=cos sum,
// [3..14]=nsq[b][d], [15..26]=vsq[b][d]
__global__ __launch_bounds__(256) void init_kernel(unsigned long long* __restrict__ m2,
                                                   unsigned* __restrict__ m1,
                                                   float* __restrict__ sums) {
  int i = blockIdx.x * 256 + threadIdx.x;
  if (i < BN) { m2[i] = ~0ULL; m1[i] = 0xFFFFFFFFu; }
  if (i < 32) sums[i] = 0.f;
}

// A[i] = (-2*pred, |pred|^2), G[i] = (-2*gt, |gt|^2)
__global__ __launch_bounds__(256) void prep_kernel(const float* __restrict__ preds,
                                                   const float* __restrict__ gts,
                                                   float4* __restrict__ A,
                                                   float4* __restrict__ G) {
  int i = blockIdx.x * 256 + threadIdx.x;
  if (i >= BN) return;
  float px = preds[3*i], py = preds[3*i+1], pz = preds[3*i+2];
  float gx = gts[3*i],   gy = gts[3*i+1],  gz = gts[3*i+2];
  A[i] = make_float4(-2.f*px, -2.f*py, -2.f*pz, px*px + py*py + pz*pz);
  G[i] = make_float4(-2.f*gx, -2.f*gy, -2.f*gz, gx*gx + gy*gy + gz*gz);
}

// mins2[b,n] = min_m P  (+ argmin over m).  rows = gts points, staged = A (preds).
__global__ __launch_bounds__(256) void pass1_kernel(const float* __restrict__ gts,
                                                    const float4* __restrict__ A,
                                                    const float4* __restrict__ G,
                                                    unsigned long long* __restrict__ m2) {
  __shared__ float4 sh[CHUNK];
  const int b = blockIdx.z, rt = blockIdx.y, ck = blockIdx.x;
  const int tid = threadIdx.x;
  const int mbase = ck * CHUNK;
  const float4* Ab = A + b * N + mbase;
#pragma unroll
  for (int j = 0; j < CHUNK / 256; ++j) sh[tid + 256*j] = Ab[tid + 256*j];
  __syncthreads();
  const int n  = rt * 256 + tid;
  const int gi = b * N + n;
  const float gx = gts[3*gi], gy = gts[3*gi+1], gz = gts[3*gi+2];
  const float gsq = G[gi].w;
  float r0 = 1e38f, r1 = 1e38f, r2 = 1e38f, r3 = 1e38f;
  int i0 = 0, i1 = 1, i2 = 2, i3 = 3;
#pragma unroll 2
  for (int j = 0; j < CHUNK; j += 4) {
    float4 q0 = sh[j], q1 = sh[j+1], q2 = sh[j+2], q3 = sh[j+3];
    float v0 = fmaf(gx, q0.x, fmaf(gy, q0.y, fmaf(gz, q0.z, q0.w)));
    float v1 = fmaf(gx, q1.x, fmaf(gy, q1.y, fmaf(gz, q1.z, q1.w)));
    float v2 = fmaf(gx, q2.x, fmaf(gy, q2.y, fmaf(gz, q2.z, q2.w)));
    float v3 = fmaf(gx, q3.x, fmaf(gy, q3.y, fmaf(gz, q3.z, q3.w)));
    if (v0 < r0) { r0 = v0; i0 = j; }
    if (v1 < r1) { r1 = v1; i1 = j+1; }
    if (v2 < r2) { r2 = v2; i2 = j+2; }
    if (v3 < r3) { r3 = v3; i3 = j+3; }
  }
  // merge 4 accumulators; tie-break to smallest index via packed compare on r
  unsigned long long p0 = ((unsigned long long)fkey(r0) << 32) | (unsigned)(mbase + i0);
  unsigned long long p1 = ((unsigned long long)fkey(r1) << 32) | (unsigned)(mbase + i1);
  unsigned long long p2 = ((unsigned long long)fkey(r2) << 32) | (unsigned)(mbase + i2);
  unsigned long long p3 = ((unsigned long long)fkey(r3) << 32) | (unsigned)(mbase + i3);
  unsigned long long pm = umin64(umin64(p0, p1), umin64(p2, p3));
  unsigned idx = (unsigned)pm;
  float rmin = funkey((unsigned)(pm >> 32));
  float d = gsq + rmin;  // full distance; monotone in rmin per-row
  atomicMin(&m2[gi], ((unsigned long long)fkey(d) << 32) | idx);
}

// mins1[b,m] = min_n P.  rows = preds points, staged = G (gts). No argmin.
__global__ __launch_bounds__(256) void pass2_kernel(const float* __restrict__ preds,
                                                    const float4* __restrict__ G,
                                                    const float4* __restrict__ A,
                                                    unsigned* __restrict__ m1) {
  __shared__ float4 sh[CHUNK];
  const int b = blockIdx.z, rt = blockIdx.y, ck = blockIdx.x;
  const int tid = threadIdx.x;
  const int nbase = ck * CHUNK;
  const float4* Gb = G + b * N + nbase;
#pragma unroll
  for (int j = 0; j < CHUNK / 256; ++j) sh[tid + 256*j] = Gb[tid + 256*j];
  __syncthreads();
  const int m  = rt * 256 + tid;
  const int gi = b * N + m;
  const float px = preds[3*gi], py = preds[3*gi+1], pz = preds[3*gi+2];
  const float psq = A[gi].w;
  float r0 = 1e38f, r1 = 1e38f, r2 = 1e38f, r3 = 1e38f;
#pragma unroll 2
  for (int j = 0; j < CHUNK; j += 4) {
    float4 q0 = sh[j], q1 = sh[j+1], q2 = sh[j+2], q3 = sh[j+3];
    r0 = fminf(r0, fmaf(px, q0.x, fmaf(py, q0.y, fmaf(pz, q0.z, q0.w))));
    r1 = fminf(r1, fmaf(px, q1.x, fmaf(py, q1.y, fmaf(pz, q1.z, q1.w))));
    r2 = fminf(r2, fmaf(px, q2.x, fmaf(py, q2.y, fmaf(pz, q2.z, q2.w))));
    r3 = fminf(r3, fmaf(px, q3.x, fmaf(py, q3.y, fmaf(pz, q3.z, q3.w))));
  }
  float rmin = fminf(fminf(r0, r1), fminf(r2, r3));
  float d = psq + rmin;
  atomicMin(&m1[gi], fkey(d));
}

__device__ __forceinline__ float block_sum(float v, float* ws) {
#pragma unroll
  for (int o = 32; o; o >>= 1) v += __shfl_down(v, o, 64);
  __syncthreads();
  if ((threadIdx.x & 63) == 0) ws[threadIdx.x >> 6] = v;
  __syncthreads();
  return ws[0] + ws[1] + ws[2] + ws[3];
}

__global__ __launch_bounds__(256) void reduce_kernel(const unsigned long long* __restrict__ m2,
                                                     const unsigned* __restrict__ m1,
                                                     unsigned* __restrict__ nidx,
                                                     float* __restrict__ sums) {
  __shared__ float ws[4];
  int i = blockIdx.x * 256 + threadIdx.x;
  unsigned long long p = m2[i];
  nidx[i] = (unsigned)p;
  float d2 = funkey((unsigned)(p >> 32));
  float d1 = funkey(m1[i]);
  float s2 = block_sum(d2, ws);
  float s1 = block_sum(d1, ws);
  if (threadIdx.x == 0) { atomicAdd(&sums[1], s2); atomicAdd(&sums[0], s1); }
}

// accumulate per-(b,d) column sums of ne^2 and ev^2 (axis-1 normalization of reference!)
__global__ __launch_bounds__(256) void edge1_kernel(const float* __restrict__ preds,
                                                    const float* __restrict__ normals,
                                                    const int* __restrict__ edges,
                                                    const unsigned* __restrict__ nidx,
                                                    float* __restrict__ sums) {
  __shared__ float ws[4];
  int b = blockIdx.y;
  int e = blockIdx.x * 256 + threadIdx.x;
  int e0 = edges[2*e], e1 = edges[2*e+1];
  const float* pb = preds   + 3*(size_t)b*N;
  const float* nb = normals + 3*(size_t)b*N;
  float vx = pb[3*e0]   - pb[3*e1];
  float vy = pb[3*e0+1] - pb[3*e1+1];
  float vz = pb[3*e0+2] - pb[3*e1+2];
  unsigned ni = nidx[b*N + e0];
  float nx = nb[3*ni], ny = nb[3*ni+1], nz = nb[3*ni+2];
  float t;
  t = block_sum(nx*nx, ws); if (threadIdx.x == 0) atomicAdd(&sums[3  + b*3 + 0], t);
  t = block_sum(ny*ny, ws); if (threadIdx.x == 0) atomicAdd(&sums[3  + b*3 + 1], t);
  t = block_sum(nz*nz, ws); if (threadIdx.x == 0) atomicAdd(&sums[3  + b*3 + 2], t);
  t = block_sum(vx*vx, ws); if (threadIdx.x == 0) atomicAdd(&sums[15 + b*3 + 0], t);
  t = block_sum(vy*vy, ws); if (threadIdx.x == 0) atomicAdd(&sums[15 + b*3 + 1], t);
  t = block_sum(vz*vz, ws); if (threadIdx.x == 0) atomicAdd(&sums[15 + b*3 + 2], t);
}

__global__ __launch_bounds__(256) void edge2_kernel(const float* __restrict__ preds,
                                                    const float* __restrict__ normals,
                                                    const int* __restrict__ edges,
                                                    const unsigned* __restrict__ nidx,
                                                    float* __restrict__ sums) {
  __shared__ float ws[4];
  int b = blockIdx.y;
  int e = blockIdx.x * 256 + threadIdx.x;
  int e0 = edges[2*e], e1 = edges[2*e+1];
  const float* pb = preds   + 3*(size_t)b*N;
  const float* nb = normals + 3*(size_t)b*N;
  float vx = pb[3*e0]   - pb[3*e1];
  float vy = pb[3*e0+1] - pb[3*e1+1];
  float vz = pb[3*e0+2] - pb[3*e1+2];
  unsigned ni = nidx[b*N + e0];
  float nx = nb[3*ni], ny = nb[3*ni+1], nz = nb[3*ni+2];
  float inn0 = 1.f / fmaxf(sqrtf(sums[3  + b*3 + 0]), 1e-12f);
  float inn1 = 1.f / fmaxf(sqrtf(sums[3  + b*3 + 1]), 1e-12f);
  float inn2 = 1.f / fmaxf(sqrtf(sums[3  + b*3 + 2]), 1e-12f);
  float inv0 = 1.f / fmaxf(sqrtf(sums[15 + b*3 + 0]), 1e-12f);
  float inv1 = 1.f / fmaxf(sqrtf(sums[15 + b*3 + 1]), 1e-12f);
  float inv2 = 1.f / fmaxf(sqrtf(sums[15 + b*3 + 2]), 1e-12f);
  float c = fabsf(nx*inn0*vx*inv0 + ny*inn1*vy*inv1 + nz*inn2*vz*inv2);
  float t = block_sum(c, ws);
  if (threadIdx.x == 0) atomicAdd(&sums[2], t);
}

__global__ void final_kernel(const float* __restrict__ sums, float* __restrict__ out) {
  if (threadIdx.x == 0 && blockIdx.x == 0) {
    float esum = 0.f;
#pragma unroll
    for (int i = 0; i < 12; ++i) esum += sums[15 + i];
    float chamfer   = (sums[0] + sums[1]) * (1.f / (float)BN);
    float edge_loss = esum * (1.f / (float)(B * E));
    float ncl       = sums[2] * (1.f / (float)(B * E));
    out[0] = 30000.f * chamfer + 240.f * edge_loss + 200000.f * ncl;
  }
}

} // namespace

extern "C" void kernel_launch(void* const* d_in, const int* in_sizes, int n_in,
                              void* d_out, int out_size, void* d_ws, size_t ws_size,
                              hipStream_t stream) {
  (void)in_sizes; (void)n_in; (void)out_size; (void)ws_size;
  const float* preds   = (const float*)d_in[0];
  const float* gts     = (const float*)d_in[1];
  const float* normals = (const float*)d_in[2];
  const int*   edges   = (const int*)d_in[3];
  char* ws = (char*)d_ws;
  // ws layout (all 16B aligned): A 512KB | G 512KB | m2 256KB | m1 128KB | nidx 128KB | sums
  float4*             A    = (float4*)(ws);
  float4*             G    = (float4*)(ws + 524288);
  unsigned long long* m2   = (unsigned long long*)(ws + 1048576);
  unsigned*           m1   = (unsigned*)(ws + 1310720);
  unsigned*           nidx = (unsigned*)(ws + 1441792);
  float*              sums = (float*)(ws + 1572864);
  float* out = (float*)d_out;

  init_kernel<<<dim3(BN/256), 256, 0, stream>>>(m2, m1, sums);
  prep_kernel<<<dim3(BN/256), 256, 0, stream>>>(preds, gts, A, G);
  pass1_kernel<<<dim3(N/CHUNK, N/256, B), 256, 0, stream>>>(gts, A, G, m2);
  pass2_kernel<<<dim3(N/CHUNK, N/256, B), 256, 0, stream>>>(preds, G, A, m1);
  reduce_kernel<<<dim3(BN/256), 256, 0, stream>>>(m2, m1, nidx, sums);
  edge1_kernel<<<dim3(E/256, B), 256, 0, stream>>>(preds, normals, edges, nidx, sums);
  edge2_kernel<<<dim3(E/256, B), 256, 0, stream>>>(preds, normals, edges, nidx, sums);
  final_kernel<<<1, 64, 0, stream>>>(sums, out);
}

// Round 3
// 99.610 us; speedup vs baseline: 1.4229x; 1.4229x over previous
//
#include <hip/hip_runtime.h>

namespace {

constexpr int B = 4;
constexpr int N = 8192;          // power of two (N = 1<<13)
constexpr int E = 24576;
constexpr int BN = B * N;
constexpr int CHUNK = 512;       // staged points per block (8 KB of float4)
constexpr int SUB = 64;          // argmin subblock granularity

// Monotonic float <-> uint mapping (total order matches float compare)
__device__ __forceinline__ unsigned fkey(float f) {
  unsigned b = __float_as_uint(f);
  return b ^ ((b & 0x80000000u) ? 0xFFFFFFFFu : 0x80000000u);
}
__device__ __forceinline__ float funkey(unsigned k) {
  unsigned b = k ^ ((k & 0x80000000u) ? 0x80000000u : 0xFFFFFFFFu);
  return __uint_as_float(b);
}

// sums layout (floats): [0]=s1 (sum mins1), [1]=s2 (sum mins2), [2]=cos sum,
// [3..14]=nsq[b][d], [15..26]=vsq[b][d]

// A[i] = (-2*pred, |pred|^2), G[i] = (-2*gt, |gt|^2); also init m2/m1/sums.
__global__ __launch_bounds__(256) void prep_kernel(const float* __restrict__ preds,
                                                   const float* __restrict__ gts,
                                                   float4* __restrict__ A,
                                                   float4* __restrict__ G,
                                                   unsigned long long* __restrict__ m2,
                                                   unsigned* __restrict__ m1,
                                                   float* __restrict__ sums) {
  int i = blockIdx.x * 256 + threadIdx.x;
  float px = preds[3*i], py = preds[3*i+1], pz = preds[3*i+2];
  float gx = gts[3*i],   gy = gts[3*i+1],  gz = gts[3*i+2];
  A[i] = make_float4(-2.f*px, -2.f*py, -2.f*pz, px*px + py*py + pz*pz);
  G[i] = make_float4(-2.f*gx, -2.f*gy, -2.f*gz, gx*gx + gy*gy + gz*gz);
  m2[i] = ~0ULL;
  m1[i] = 0xFFFFFFFFu;
  if (i < 32) sums[i] = 0.f;
}

// Generic min pass. R = rows array, S = staged (reduced-over) array.
// Row constants recovered as x = -0.5*R.x (bitwise-exact inverse of -2x).
// v = x*S.x + y*S.y + z*S.z + S.w  (= -2*dot + |s|^2);  d = R.w + v.
// ARGMIN: track 64-point subblock of the min, pack (fkey(d)<<32 | subbase).
template<bool ARGMIN>
__global__ __launch_bounds__(256) void pass_kernel(const float4* __restrict__ R,
                                                   const float4* __restrict__ S,
                                                   unsigned long long* __restrict__ m64,
                                                   unsigned* __restrict__ m32) {
  __shared__ float4 sh[CHUNK];
  const int b = blockIdx.z, rt = blockIdx.y, ck = blockIdx.x;
  const int tid = threadIdx.x;
  const int base = ck * CHUNK;
  const float4* Sb = S + b * N + base;
  sh[tid]       = Sb[tid];
  sh[tid + 256] = Sb[tid + 256];
  __syncthreads();
  const int n0 = rt * 512 + tid, n1 = n0 + 256;
  const int gi0 = b * N + n0, gi1 = b * N + n1;
  float4 r0 = R[gi0], r1 = R[gi1];
  const float x0 = -0.5f*r0.x, y0 = -0.5f*r0.y, z0 = -0.5f*r0.z, w0 = r0.w;
  const float x1 = -0.5f*r1.x, y1 = -0.5f*r1.y, z1 = -0.5f*r1.z, w1 = r1.w;
  float best0 = 3.4e38f, best1 = 3.4e38f;
  int sb0 = 0, sb1 = 0;
  for (int sb = 0; sb < CHUNK; sb += SUB) {
    float a00 = 3.4e38f, a01 = 3.4e38f, a10 = 3.4e38f, a11 = 3.4e38f;
#pragma unroll 4
    for (int j = sb; j < sb + SUB; j += 4) {
      float4 q0 = sh[j], q1 = sh[j+1], q2 = sh[j+2], q3 = sh[j+3];
      float v00 = fmaf(x0, q0.x, fmaf(y0, q0.y, fmaf(z0, q0.z, q0.w)));
      float v01 = fmaf(x0, q1.x, fmaf(y0, q1.y, fmaf(z0, q1.z, q1.w)));
      float v02 = fmaf(x0, q2.x, fmaf(y0, q2.y, fmaf(z0, q2.z, q2.w)));
      float v03 = fmaf(x0, q3.x, fmaf(y0, q3.y, fmaf(z0, q3.z, q3.w)));
      float v10 = fmaf(x1, q0.x, fmaf(y1, q0.y, fmaf(z1, q0.z, q0.w)));
      float v11 = fmaf(x1, q1.x, fmaf(y1, q1.y, fmaf(z1, q1.z, q1.w)));
      float v12 = fmaf(x1, q2.x, fmaf(y1, q2.y, fmaf(z1, q2.z, q2.w)));
      float v13 = fmaf(x1, q3.x, fmaf(y1, q3.y, fmaf(z1, q3.z, q3.w)));
      a00 = fminf(fminf(a00, v00), v01);   // -> v_min3_f32
      a01 = fminf(fminf(a01, v02), v03);
      a10 = fminf(fminf(a10, v10), v11);
      a11 = fminf(fminf(a11, v12), v13);
    }
    if (ARGMIN) {
      float s0 = fminf(a00, a01), s1 = fminf(a10, a11);
      if (s0 < best0) { best0 = s0; sb0 = base + sb; }  // strict <: first subblock wins ties
      if (s1 < best1) { best1 = s1; sb1 = base + sb; }
    } else {
      best0 = fminf(best0, fminf(a00, a01));
      best1 = fminf(best1, fminf(a10, a11));
    }
  }
  float d0 = w0 + best0, d1 = w1 + best1;
  if (ARGMIN) {
    atomicMin(&m64[gi0], ((unsigned long long)fkey(d0) << 32) | (unsigned)sb0);
    atomicMin(&m64[gi1], ((unsigned long long)fkey(d1) << 32) | (unsigned)sb1);
  } else {
    atomicMin(&m32[gi0], fkey(d0));
    atomicMin(&m32[gi1], fkey(d1));
  }
}

// One wave per row: re-scan the winning 64-point subblock, bitwise-identical
// arithmetic, first lane matching the stored min key is the argmin.
__global__ __launch_bounds__(256) void rescan_kernel(const float4* __restrict__ G,
                                                     const float4* __restrict__ A,
                                                     const unsigned long long* __restrict__ m2,
                                                     unsigned* __restrict__ nidx) {
  const int row  = (blockIdx.x * 256 + threadIdx.x) >> 6;   // 4 rows per block
  const int lane = threadIdx.x & 63;
  const int b = row >> 13;          // / N
  const int n = row & (N - 1);
  const int gi = b * N + n;
  unsigned long long p = m2[gi];
  const unsigned kd = (unsigned)(p >> 32);
  const int base = (int)(unsigned)p;
  float4 r = G[gi];
  const float x = -0.5f*r.x, y = -0.5f*r.y, z = -0.5f*r.z, w = r.w;
  float4 q = A[b * N + base + lane];
  float v = fmaf(x, q.x, fmaf(y, q.y, fmaf(z, q.z, q.w)));
  float d = w + v;
  unsigned long long mask = __ballot(fkey(d) == kd);
  if (lane == 0) nidx[gi] = mask ? (unsigned)(base + __ffsll(mask) - 1) : (unsigned)base;
}

__device__ __forceinline__ float block_sum(float v, float* ws) {
#pragma unroll
  for (int o = 32; o; o >>= 1) v += __shfl_down(v, o, 64);
  __syncthreads();
  if ((threadIdx.x & 63) == 0) ws[threadIdx.x >> 6] = v;
  __syncthreads();
  return ws[0] + ws[1] + ws[2] + ws[3];
}

__global__ __launch_bounds__(256) void reduce_kernel(const unsigned long long* __restrict__ m2,
                                                     const unsigned* __restrict__ m1,
                                                     float* __restrict__ sums) {
  __shared__ float ws[4];
  int i = blockIdx.x * 256 + threadIdx.x;
  float d2 = funkey((unsigned)(m2[i] >> 32));
  float d1 = funkey(m1[i]);
  float s2 = block_sum(d2, ws);
  float s1 = block_sum(d1, ws);
  if (threadIdx.x == 0) { atomicAdd(&sums[1], s2); atomicAdd(&sums[0], s1); }
}

// per-(b,d) column sums of ne^2 and ev^2 (axis-1 normalization of reference!)
__global__ __launch_bounds__(256) void edge1_kernel(const float* __restrict__ preds,
                                                    const float* __restrict__ normals,
                                                    const int* __restrict__ edges,
                                                    const unsigned* __restrict__ nidx,
                                                    float* __restrict__ sums) {
  __shared__ float ws[4];
  int b = blockIdx.y;
  int e = blockIdx.x * 256 + threadIdx.x;
  int e0 = edges[2*e], e1 = edges[2*e+1];
  const float* pb = preds   + 3*(size_t)b*N;
  const float* nb = normals + 3*(size_t)b*N;
  float vx = pb[3*e0]   - pb[3*e1];
  float vy = pb[3*e0+1] - pb[3*e1+1];
  float vz = pb[3*e0+2] - pb[3*e1+2];
  unsigned ni = nidx[b*N + e0];
  float nx = nb[3*ni], ny = nb[3*ni+1], nz = nb[3*ni+2];
  float t;
  t = block_sum(nx*nx, ws); if (threadIdx.x == 0) atomicAdd(&sums[3  + b*3 + 0], t);
  t = block_sum(ny*ny, ws); if (threadIdx.x == 0) atomicAdd(&sums[3  + b*3 + 1], t);
  t = block_sum(nz*nz, ws); if (threadIdx.x == 0) atomicAdd(&sums[3  + b*3 + 2], t);
  t = block_sum(vx*vx, ws); if (threadIdx.x == 0) atomicAdd(&sums[15 + b*3 + 0], t);
  t = block_sum(vy*vy, ws); if (threadIdx.x == 0) atomicAdd(&sums[15 + b*3 + 1], t);
  t = block_sum(vz*vz, ws); if (threadIdx.x == 0) atomicAdd(&sums[15 + b*3 + 2], t);
}

__global__ __launch_bounds__(256) void edge2_kernel(const float* __restrict__ preds,
                                                    const float* __restrict__ normals,
                                                    const int* __restrict__ edges,
                                                    const unsigned* __restrict__ nidx,
                                                    float* __restrict__ sums) {
  __shared__ float ws[4];
  int b = blockIdx.y;
  int e = blockIdx.x * 256 + threadIdx.x;
  int e0 = edges[2*e], e1 = edges[2*e+1];
  const float* pb = preds   + 3*(size_t)b*N;
  const float* nb = normals + 3*(size_t)b*N;
  float vx = pb[3*e0]   - pb[3*e1];
  float vy = pb[3*e0+1] - pb[3*e1+1];
  float vz = pb[3*e0+2] - pb[3*e1+2];
  unsigned ni = nidx[b*N + e0];
  float nx = nb[3*ni], ny = nb[3*ni+1], nz = nb[3*ni+2];
  float inn0 = 1.f / fmaxf(sqrtf(sums[3  + b*3 + 0]), 1e-12f);
  float inn1 = 1.f / fmaxf(sqrtf(sums[3  + b*3 + 1]), 1e-12f);
  float inn2 = 1.f / fmaxf(sqrtf(sums[3  + b*3 + 2]), 1e-12f);
  float inv0 = 1.f / fmaxf(sqrtf(sums[15 + b*3 + 0]), 1e-12f);
  float inv1 = 1.f / fmaxf(sqrtf(sums[15 + b*3 + 1]), 1e-12f);
  float inv2 = 1.f / fmaxf(sqrtf(sums[15 + b*3 + 2]), 1e-12f);
  float c = fabsf(nx*inn0*vx*inv0 + ny*inn1*vy*inv1 + nz*inn2*vz*inv2);
  float t = block_sum(c, ws);
  if (threadIdx.x == 0) atomicAdd(&sums[2], t);
}

__global__ void final_kernel(const float* __restrict__ sums, float* __restrict__ out) {
  if (threadIdx.x == 0 && blockIdx.x == 0) {
    float esum = 0.f;
#pragma unroll
    for (int i = 0; i < 12; ++i) esum += sums[15 + i];
    float chamfer   = (sums[0] + sums[1]) * (1.f / (float)BN);
    float edge_loss = esum * (1.f / (float)(B * E));
    float ncl       = sums[2] * (1.f / (float)(B * E));
    out[0] = 30000.f * chamfer + 240.f * edge_loss + 200000.f * ncl;
  }
}

} // namespace

extern "C" void kernel_launch(void* const* d_in, const int* in_sizes, int n_in,
                              void* d_out, int out_size, void* d_ws, size_t ws_size,
                              hipStream_t stream) {
  (void)in_sizes; (void)n_in; (void)out_size; (void)ws_size;
  const float* preds   = (const float*)d_in[0];
  const float* gts     = (const float*)d_in[1];
  const float* normals = (const float*)d_in[2];
  const int*   edges   = (const int*)d_in[3];
  char* ws = (char*)d_ws;
  // ws layout: A 512KB | G 512KB | m2 256KB | m1 128KB | nidx 128KB | sums
  float4*             A    = (float4*)(ws);
  float4*             G    = (float4*)(ws + 524288);
  unsigned long long* m2   = (unsigned long long*)(ws + 1048576);
  unsigned*           m1   = (unsigned*)(ws + 1310720);
  unsigned*           nidx = (unsigned*)(ws + 1441792);
  float*              sums = (float*)(ws + 1572864);
  float* out = (float*)d_out;

  prep_kernel<<<dim3(BN/256), 256, 0, stream>>>(preds, gts, A, G, m2, m1, sums);
  // pass1: rows = gts (G), staged = preds (A) -> m2 (min over m, + subblock)
  pass_kernel<true><<<dim3(N/CHUNK, N/512, B), 256, 0, stream>>>(G, A, m2, nullptr);
  // pass2: rows = preds (A), staged = gts (G) -> m1 (min over n)
  pass_kernel<false><<<dim3(N/CHUNK, N/512, B), 256, 0, stream>>>(A, G, nullptr, m1);
  // one wave per row -> BN waves -> BN*64/256 = BN/4 blocks  (R2 bug: was /64 too few)
  rescan_kernel<<<dim3(BN/4), 256, 0, stream>>>(G, A, m2, nidx);
  reduce_kernel<<<dim3(BN/256), 256, 0, stream>>>(m2, m1, sums);
  edge1_kernel<<<dim3(E/256, B), 256, 0, stream>>>(preds, normals, edges, nidx, sums);
  edge2_kernel<<<dim3(E/256, B), 256, 0, stream>>>(preds, normals, edges, nidx, sums);
  final_kernel<<<1, 64, 0, stream>>>(sums, out);
}

// Round 4
// 98.421 us; speedup vs baseline: 1.4401x; 1.0121x over previous
//
#include <hip/hip_runtime.h>

namespace {

constexpr int B = 4;
constexpr int N = 8192;          // power of two (N = 1<<13)
constexpr int E = 24576;
constexpr int BN = B * N;
constexpr int CHUNK = 256;       // staged points per block (4 KB of float4)
constexpr int SUB = 64;          // argmin subblock granularity
constexpr int RT = 8;            // rows per thread (register-tiled)

// Monotonic float <-> uint mapping (total order matches float compare)
__device__ __forceinline__ unsigned fkey(float f) {
  unsigned b = __float_as_uint(f);
  return b ^ ((b & 0x80000000u) ? 0xFFFFFFFFu : 0x80000000u);
}
__device__ __forceinline__ float funkey(unsigned k) {
  unsigned b = k ^ ((k & 0x80000000u) ? 0x80000000u : 0xFFFFFFFFu);
  return __uint_as_float(b);
}

// sums layout (floats): [0]=s1 (sum mins1), [1]=s2 (sum mins2), [2]=cos sum,
// [3..14]=nsq[b][d], [15..26]=vsq[b][d]

// A[i] = (-2*pred, |pred|^2), G[i] = (-2*gt, |gt|^2); also init m2/m1/sums.
__global__ __launch_bounds__(256) void prep_kernel(const float* __restrict__ preds,
                                                   const float* __restrict__ gts,
                                                   float4* __restrict__ A,
                                                   float4* __restrict__ G,
                                                   unsigned long long* __restrict__ m2,
                                                   unsigned* __restrict__ m1,
                                                   float* __restrict__ sums) {
  int i = blockIdx.x * 256 + threadIdx.x;
  float px = preds[3*i], py = preds[3*i+1], pz = preds[3*i+2];
  float gx = gts[3*i],   gy = gts[3*i+1],  gz = gts[3*i+2];
  A[i] = make_float4(-2.f*px, -2.f*py, -2.f*pz, px*px + py*py + pz*pz);
  G[i] = make_float4(-2.f*gx, -2.f*gy, -2.f*gz, gx*gx + gy*gy + gz*gz);
  m2[i] = ~0ULL;
  m1[i] = 0xFFFFFFFFu;
  if (i < 32) sums[i] = 0.f;
}

// Min pass, register-tiled: each thread owns RT=8 rows (constants in VGPRs);
// one broadcast ds_read_b128 per staged point serves 8 rows -> 3.5 VALU/pair.
// v = x*S.x + y*S.y + z*S.z + S.w (= -2*dot + |s|^2);  d = R.w + v.
// ARGMIN: per-row 64-point subblock tracking, packed (fkey(d)<<32 | subbase).
template<bool ARGMIN>
__global__ __launch_bounds__(256) void pass_kernel(const float4* __restrict__ R,
                                                   const float4* __restrict__ S,
                                                   unsigned long long* __restrict__ m64,
                                                   unsigned* __restrict__ m32) {
  __shared__ float4 sh[CHUNK];
  const int b = blockIdx.z, rt = blockIdx.y, ck = blockIdx.x;
  const int tid = threadIdx.x;
  const int base = ck * CHUNK;
  sh[tid] = S[b * N + base + tid];
  __syncthreads();
  float x[RT], y[RT], z[RT], w[RT], best[RT];
  int sbb[RT];
#pragma unroll
  for (int i = 0; i < RT; ++i) {
    float4 r = R[b * N + rt * (256 * RT) + i * 256 + tid];
    x[i] = -0.5f * r.x; y[i] = -0.5f * r.y; z[i] = -0.5f * r.z; w[i] = r.w;
    best[i] = 3.4e38f; sbb[i] = 0;
  }
  for (int sb = 0; sb < CHUNK; sb += SUB) {
    float a[RT];
#pragma unroll
    for (int i = 0; i < RT; ++i) a[i] = 3.4e38f;
#pragma unroll 2
    for (int j = sb; j < sb + SUB; j += 2) {
      float4 q0 = sh[j], q1 = sh[j + 1];
#pragma unroll
      for (int i = 0; i < RT; ++i) {
        float v0 = fmaf(x[i], q0.x, fmaf(y[i], q0.y, fmaf(z[i], q0.z, q0.w)));
        float v1 = fmaf(x[i], q1.x, fmaf(y[i], q1.y, fmaf(z[i], q1.z, q1.w)));
        a[i] = fminf(fminf(a[i], v0), v1);   // -> v_min3_f32
      }
    }
    if (ARGMIN) {
#pragma unroll
      for (int i = 0; i < RT; ++i)
        if (a[i] < best[i]) { best[i] = a[i]; sbb[i] = base + sb; }  // strict <: earliest subblock wins ties
    } else {
#pragma unroll
      for (int i = 0; i < RT; ++i) best[i] = fminf(best[i], a[i]);
    }
  }
#pragma unroll
  for (int i = 0; i < RT; ++i) {
    const int gi = b * N + rt * (256 * RT) + i * 256 + tid;
    float d = w[i] + best[i];
    if (ARGMIN) {
      atomicMin(&m64[gi], ((unsigned long long)fkey(d) << 32) | (unsigned)sbb[i]);
    } else {
      atomicMin(&m32[gi], fkey(d));
    }
  }
}

// One wave per row: re-scan the winning 64-point subblock, bitwise-identical
// arithmetic, first lane matching the stored min key is the argmin.
__global__ __launch_bounds__(256) void rescan_kernel(const float4* __restrict__ G,
                                                     const float4* __restrict__ A,
                                                     const unsigned long long* __restrict__ m2,
                                                     unsigned* __restrict__ nidx) {
  const int row  = (blockIdx.x * 256 + threadIdx.x) >> 6;   // 4 rows per block
  const int lane = threadIdx.x & 63;
  const int b = row >> 13;          // / N
  const int n = row & (N - 1);
  const int gi = b * N + n;
  unsigned long long p = m2[gi];
  const unsigned kd = (unsigned)(p >> 32);
  const int base = (int)(unsigned)p;
  float4 r = G[gi];
  const float x = -0.5f*r.x, y = -0.5f*r.y, z = -0.5f*r.z, w = r.w;
  float4 q = A[b * N + base + lane];
  float v = fmaf(x, q.x, fmaf(y, q.y, fmaf(z, q.z, q.w)));
  float d = w + v;
  unsigned long long mask = __ballot(fkey(d) == kd);
  if (lane == 0) nidx[gi] = mask ? (unsigned)(base + __ffsll(mask) - 1) : (unsigned)base;
}

__device__ __forceinline__ float block_sum(float v, float* ws) {
#pragma unroll
  for (int o = 32; o; o >>= 1) v += __shfl_down(v, o, 64);
  __syncthreads();
  if ((threadIdx.x & 63) == 0) ws[threadIdx.x >> 6] = v;
  __syncthreads();
  return ws[0] + ws[1] + ws[2] + ws[3];
}

__global__ __launch_bounds__(256) void reduce_kernel(const unsigned long long* __restrict__ m2,
                                                     const unsigned* __restrict__ m1,
                                                     float* __restrict__ sums) {
  __shared__ float ws[4];
  int i = blockIdx.x * 256 + threadIdx.x;
  float d2 = funkey((unsigned)(m2[i] >> 32));
  float d1 = funkey(m1[i]);
  float s2 = block_sum(d2, ws);
  float s1 = block_sum(d1, ws);
  if (threadIdx.x == 0) { atomicAdd(&sums[1], s2); atomicAdd(&sums[0], s1); }
}

// per-(b,d) column sums of ne^2 and ev^2 (axis-1 normalization of reference!)
__global__ __launch_bounds__(256) void edge1_kernel(const float* __restrict__ preds,
                                                    const float* __restrict__ normals,
                                                    const int* __restrict__ edges,
                                                    const unsigned* __restrict__ nidx,
                                                    float* __restrict__ sums) {
  __shared__ float ws[4];
  int b = blockIdx.y;
  int e = blockIdx.x * 256 + threadIdx.x;
  int e0 = edges[2*e], e1 = edges[2*e+1];
  const float* pb = preds   + 3*(size_t)b*N;
  const float* nb = normals + 3*(size_t)b*N;
  float vx = pb[3*e0]   - pb[3*e1];
  float vy = pb[3*e0+1] - pb[3*e1+1];
  float vz = pb[3*e0+2] - pb[3*e1+2];
  unsigned ni = nidx[b*N + e0];
  float nx = nb[3*ni], ny = nb[3*ni+1], nz = nb[3*ni+2];
  float t;
  t = block_sum(nx*nx, ws); if (threadIdx.x == 0) atomicAdd(&sums[3  + b*3 + 0], t);
  t = block_sum(ny*ny, ws); if (threadIdx.x == 0) atomicAdd(&sums[3  + b*3 + 1], t);
  t = block_sum(nz*nz, ws); if (threadIdx.x == 0) atomicAdd(&sums[3  + b*3 + 2], t);
  t = block_sum(vx*vx, ws); if (threadIdx.x == 0) atomicAdd(&sums[15 + b*3 + 0], t);
  t = block_sum(vy*vy, ws); if (threadIdx.x == 0) atomicAdd(&sums[15 + b*3 + 1], t);
  t = block_sum(vz*vz, ws); if (threadIdx.x == 0) atomicAdd(&sums[15 + b*3 + 2], t);
}

__global__ __launch_bounds__(256) void edge2_kernel(const float* __restrict__ preds,
                                                    const float* __restrict__ normals,
                                                    const int* __restrict__ edges,
                                                    const unsigned* __restrict__ nidx,
                                                    float* __restrict__ sums) {
  __shared__ float ws[4];
  int b = blockIdx.y;
  int e = blockIdx.x * 256 + threadIdx.x;
  int e0 = edges[2*e], e1 = edges[2*e+1];
  const float* pb = preds   + 3*(size_t)b*N;
  const float* nb = normals + 3*(size_t)b*N;
  float vx = pb[3*e0]   - pb[3*e1];
  float vy = pb[3*e0+1] - pb[3*e1+1];
  float vz = pb[3*e0+2] - pb[3*e1+2];
  unsigned ni = nidx[b*N + e0];
  float nx = nb[3*ni], ny = nb[3*ni+1], nz = nb[3*ni+2];
  float inn0 = 1.f / fmaxf(sqrtf(sums[3  + b*3 + 0]), 1e-12f);
  float inn1 = 1.f / fmaxf(sqrtf(sums[3  + b*3 + 1]), 1e-12f);
  float inn2 = 1.f / fmaxf(sqrtf(sums[3  + b*3 + 2]), 1e-12f);
  float inv0 = 1.f / fmaxf(sqrtf(sums[15 + b*3 + 0]), 1e-12f);
  float inv1 = 1.f / fmaxf(sqrtf(sums[15 + b*3 + 1]), 1e-12f);
  float inv2 = 1.f / fmaxf(sqrtf(sums[15 + b*3 + 2]), 1e-12f);
  float c = fabsf(nx*inn0*vx*inv0 + ny*inn1*vy*inv1 + nz*inn2*vz*inv2);
  float t = block_sum(c, ws);
  if (threadIdx.x == 0) atomicAdd(&sums[2], t);
}

__global__ void final_kernel(const float* __restrict__ sums, float* __restrict__ out) {
  if (threadIdx.x == 0 && blockIdx.x == 0) {
    float esum = 0.f;
#pragma unroll
    for (int i = 0; i < 12; ++i) esum += sums[15 + i];
    float chamfer   = (sums[0] + sums[1]) * (1.f / (float)BN);
    float edge_loss = esum * (1.f / (float)(B * E));
    float ncl       = sums[2] * (1.f / (float)(B * E));
    out[0] = 30000.f * chamfer + 240.f * edge_loss + 200000.f * ncl;
  }
}

} // namespace

extern "C" void kernel_launch(void* const* d_in, const int* in_sizes, int n_in,
                              void* d_out, int out_size, void* d_ws, size_t ws_size,
                              hipStream_t stream) {
  (void)in_sizes; (void)n_in; (void)out_size; (void)ws_size;
  const float* preds   = (const float*)d_in[0];
  const float* gts     = (const float*)d_in[1];
  const float* normals = (const float*)d_in[2];
  const int*   edges   = (const int*)d_in[3];
  char* ws = (char*)d_ws;
  // ws layout: A 512KB | G 512KB | m2 256KB | m1 128KB | nidx 128KB | sums
  float4*             A    = (float4*)(ws);
  float4*             G    = (float4*)(ws + 524288);
  unsigned long long* m2   = (unsigned long long*)(ws + 1048576);
  unsigned*           m1   = (unsigned*)(ws + 1310720);
  unsigned*           nidx = (unsigned*)(ws + 1441792);
  float*              sums = (float*)(ws + 1572864);
  float* out = (float*)d_out;

  prep_kernel<<<dim3(BN/256), 256, 0, stream>>>(preds, gts, A, G, m2, m1, sums);
  // pass1: rows = gts (G), staged = preds (A) -> m2 (min over m, + subblock)
  pass_kernel<true><<<dim3(N/CHUNK, N/(256*RT), B), 256, 0, stream>>>(G, A, m2, nullptr);
  // pass2: rows = preds (A), staged = gts (G) -> m1 (min over n)
  pass_kernel<false><<<dim3(N/CHUNK, N/(256*RT), B), 256, 0, stream>>>(A, G, nullptr, m1);
  // one wave per row -> BN waves -> BN/4 blocks of 256
  rescan_kernel<<<dim3(BN/4), 256, 0, stream>>>(G, A, m2, nidx);
  reduce_kernel<<<dim3(BN/256), 256, 0, stream>>>(m2, m1, sums);
  edge1_kernel<<<dim3(E/256, B), 256, 0, stream>>>(preds, normals, edges, nidx, sums);
  edge2_kernel<<<dim3(E/256, B), 256, 0, stream>>>(preds, normals, edges, nidx, sums);
  final_kernel<<<1, 64, 0, stream>>>(sums, out);
}

// Round 5
// 94.239 us; speedup vs baseline: 1.5040x; 1.0444x over previous
//
#include <hip/hip_runtime.h>

namespace {

constexpr int B = 4;
constexpr int N = 8192;          // power of two (N = 1<<13)
constexpr int E = 24576;
constexpr int BN = B * N;
constexpr int CHUNK = 512;       // staged points per block (8 KB of float4)
constexpr int SUB = 64;          // argmin subblock granularity
constexpr int RT = 8;            // rows per thread (register-tiled)

// Monotonic float <-> uint mapping (total order matches float compare)
__device__ __forceinline__ unsigned fkey(float f) {
  unsigned b = __float_as_uint(f);
  return b ^ ((b & 0x80000000u) ? 0xFFFFFFFFu : 0x80000000u);
}
__device__ __forceinline__ float funkey(unsigned k) {
  unsigned b = k ^ ((k & 0x80000000u) ? 0x80000000u : 0xFFFFFFFFu);
  return __uint_as_float(b);
}
// 3-input min in one instruction (T17; don't rely on clang fusing fminf pairs)
__device__ __forceinline__ float min3f(float a, float b, float c) {
  float d;
  asm("v_min3_f32 %0, %1, %2, %3" : "=v"(d) : "v"(a), "v"(b), "v"(c));
  return d;
}

// sums layout (floats): [0]=s1 (sum mins1), [1]=s2 (sum mins2), [2]=cos sum,
// [3..14]=nsq[b][d], [15..26]=vsq[b][d]

// A[i] = (-2*pred, |pred|^2), G[i] = (-2*gt, |gt|^2); also init m2/m1/sums.
__global__ __launch_bounds__(256) void prep_kernel(const float* __restrict__ preds,
                                                   const float* __restrict__ gts,
                                                   float4* __restrict__ A,
                                                   float4* __restrict__ G,
                                                   unsigned long long* __restrict__ m2,
                                                   unsigned* __restrict__ m1,
                                                   float* __restrict__ sums) {
  int i = blockIdx.x * 256 + threadIdx.x;
  float px = preds[3*i], py = preds[3*i+1], pz = preds[3*i+2];
  float gx = gts[3*i],   gy = gts[3*i+1],  gz = gts[3*i+2];
  A[i] = make_float4(-2.f*px, -2.f*py, -2.f*pz, px*px + py*py + pz*pz);
  G[i] = make_float4(-2.f*gx, -2.f*gy, -2.f*gz, gx*gx + gy*gy + gz*gz);
  m2[i] = ~0ULL;
  m1[i] = 0xFFFFFFFFu;
  if (i < 32) sums[i] = 0.f;
}

// Fused min pass: blockIdx.z = b + 4*which.
//   which=0: rows = gts (G), staged = preds (A) -> m2 (min over m, + subblock argmin)
//   which=1: rows = preds (A), staged = gts (G) -> m1 (min over n)
// Each thread owns RT=8 rows (constants in VGPRs); one broadcast ds_read_b128
// per staged point serves 8 rows. Inner 64-pt loop fully unrolled -> imm DS offsets.
// v = x*S.x + y*S.y + z*S.z + S.w (= -2*dot + |s|^2);  d = R.w + v.
__global__ __launch_bounds__(256) void pass_fused(const float4* __restrict__ A,
                                                  const float4* __restrict__ G,
                                                  unsigned long long* __restrict__ m2,
                                                  unsigned* __restrict__ m1) {
  __shared__ float4 sh[CHUNK];
  const int which = blockIdx.z >> 2, b = blockIdx.z & 3;
  const float4* __restrict__ R = which ? A : G;
  const float4* __restrict__ S = which ? G : A;
  const int rt = blockIdx.y, ck = blockIdx.x;
  const int tid = threadIdx.x;
  const int base = ck * CHUNK;
  const float4* Sb = S + b * N + base;
  sh[tid]       = Sb[tid];
  sh[tid + 256] = Sb[tid + 256];
  __syncthreads();
  float x[RT], y[RT], z[RT], w[RT], best[RT];
  int sbb[RT];
#pragma unroll
  for (int i = 0; i < RT; ++i) {
    float4 r = R[b * N + rt * (256 * RT) + i * 256 + tid];
    x[i] = -0.5f * r.x; y[i] = -0.5f * r.y; z[i] = -0.5f * r.z; w[i] = r.w;
    best[i] = 3.4e38f; sbb[i] = 0;
  }
  for (int sb = 0; sb < CHUNK; sb += SUB) {
    float a[RT];
#pragma unroll
    for (int i = 0; i < RT; ++i) a[i] = 3.4e38f;
    const float4* shp = &sh[sb];
#pragma unroll
    for (int j = 0; j < SUB; j += 2) {
      float4 q0 = shp[j], q1 = shp[j + 1];
#pragma unroll
      for (int i = 0; i < RT; ++i) {
        float v0 = fmaf(x[i], q0.x, fmaf(y[i], q0.y, fmaf(z[i], q0.z, q0.w)));
        float v1 = fmaf(x[i], q1.x, fmaf(y[i], q1.y, fmaf(z[i], q1.z, q1.w)));
        a[i] = min3f(a[i], v0, v1);
      }
    }
#pragma unroll
    for (int i = 0; i < RT; ++i)
      if (a[i] < best[i]) { best[i] = a[i]; sbb[i] = base + sb; }  // strict <: earliest subblock wins ties
  }
#pragma unroll
  for (int i = 0; i < RT; ++i) {
    const int gi = b * N + rt * (256 * RT) + i * 256 + tid;
    float d = w[i] + best[i];
    if (which == 0) {
      atomicMin(&m2[gi], ((unsigned long long)fkey(d) << 32) | (unsigned)sbb[i]);
    } else {
      atomicMin(&m1[gi], fkey(d));
    }
  }
}

// One wave per row: re-scan the winning 64-point subblock, bitwise-identical
// arithmetic, first lane matching the stored min key is the argmin.
__global__ __launch_bounds__(256) void rescan_kernel(const float4* __restrict__ G,
                                                     const float4* __restrict__ A,
                                                     const unsigned long long* __restrict__ m2,
                                                     unsigned* __restrict__ nidx) {
  const int row  = (blockIdx.x * 256 + threadIdx.x) >> 6;   // 4 rows per block
  const int lane = threadIdx.x & 63;
  const int b = row >> 13;          // / N
  const int n = row & (N - 1);
  const int gi = b * N + n;
  unsigned long long p = m2[gi];
  const unsigned kd = (unsigned)(p >> 32);
  const int base = (int)(unsigned)p;
  float4 r = G[gi];
  const float x = -0.5f*r.x, y = -0.5f*r.y, z = -0.5f*r.z, w = r.w;
  float4 q = A[b * N + base + lane];
  float v = fmaf(x, q.x, fmaf(y, q.y, fmaf(z, q.z, q.w)));
  float d = w + v;
  unsigned long long mask = __ballot(fkey(d) == kd);
  if (lane == 0) nidx[gi] = mask ? (unsigned)(base + __ffsll(mask) - 1) : (unsigned)base;
}

__device__ __forceinline__ float block_sum(float v, float* ws) {
#pragma unroll
  for (int o = 32; o; o >>= 1) v += __shfl_down(v, o, 64);
  __syncthreads();
  if ((threadIdx.x & 63) == 0) ws[threadIdx.x >> 6] = v;
  __syncthreads();
  return ws[0] + ws[1] + ws[2] + ws[3];
}

__global__ __launch_bounds__(256) void reduce_kernel(const unsigned long long* __restrict__ m2,
                                                     const unsigned* __restrict__ m1,
                                                     float* __restrict__ sums) {
  __shared__ float ws[4];
  int i = blockIdx.x * 256 + threadIdx.x;
  float d2 = funkey((unsigned)(m2[i] >> 32));
  float d1 = funkey(m1[i]);
  float s2 = block_sum(d2, ws);
  float s1 = block_sum(d1, ws);
  if (threadIdx.x == 0) { atomicAdd(&sums[1], s2); atomicAdd(&sums[0], s1); }
}

// per-(b,d) column sums of ne^2 and ev^2 (axis-1 normalization of reference!)
__global__ __launch_bounds__(256) void edge1_kernel(const float* __restrict__ preds,
                                                    const float* __restrict__ normals,
                                                    const int* __restrict__ edges,
                                                    const unsigned* __restrict__ nidx,
                                                    float* __restrict__ sums) {
  __shared__ float ws[4];
  int b = blockIdx.y;
  int e = blockIdx.x * 256 + threadIdx.x;
  int e0 = edges[2*e], e1 = edges[2*e+1];
  const float* pb = preds   + 3*(size_t)b*N;
  const float* nb = normals + 3*(size_t)b*N;
  float vx = pb[3*e0]   - pb[3*e1];
  float vy = pb[3*e0+1] - pb[3*e1+1];
  float vz = pb[3*e0+2] - pb[3*e1+2];
  unsigned ni = nidx[b*N + e0];
  float nx = nb[3*ni], ny = nb[3*ni+1], nz = nb[3*ni+2];
  float t;
  t = block_sum(nx*nx, ws); if (threadIdx.x == 0) atomicAdd(&sums[3  + b*3 + 0], t);
  t = block_sum(ny*ny, ws); if (threadIdx.x == 0) atomicAdd(&sums[3  + b*3 + 1], t);
  t = block_sum(nz*nz, ws); if (threadIdx.x == 0) atomicAdd(&sums[3  + b*3 + 2], t);
  t = block_sum(vx*vx, ws); if (threadIdx.x == 0) atomicAdd(&sums[15 + b*3 + 0], t);
  t = block_sum(vy*vy, ws); if (threadIdx.x == 0) atomicAdd(&sums[15 + b*3 + 1], t);
  t = block_sum(vz*vz, ws); if (threadIdx.x == 0) atomicAdd(&sums[15 + b*3 + 2], t);
}

__global__ __launch_bounds__(256) void edge2_kernel(const float* __restrict__ preds,
                                                    const float* __restrict__ normals,
                                                    const int* __restrict__ edges,
                                                    const unsigned* __restrict__ nidx,
                                                    float* __restrict__ sums) {
  __shared__ float ws[4];
  int b = blockIdx.y;
  int e = blockIdx.x * 256 + threadIdx.x;
  int e0 = edges[2*e], e1 = edges[2*e+1];
  const float* pb = preds   + 3*(size_t)b*N;
  const float* nb = normals + 3*(size_t)b*N;
  float vx = pb[3*e0]   - pb[3*e1];
  float vy = pb[3*e0+1] - pb[3*e1+1];
  float vz = pb[3*e0+2] - pb[3*e1+2];
  unsigned ni = nidx[b*N + e0];
  float nx = nb[3*ni], ny = nb[3*ni+1], nz = nb[3*ni+2];
  float inn0 = 1.f / fmaxf(sqrtf(sums[3  + b*3 + 0]), 1e-12f);
  float inn1 = 1.f / fmaxf(sqrtf(sums[3  + b*3 + 1]), 1e-12f);
  float inn2 = 1.f / fmaxf(sqrtf(sums[3  + b*3 + 2]), 1e-12f);
  float inv0 = 1.f / fmaxf(sqrtf(sums[15 + b*3 + 0]), 1e-12f);
  float inv1 = 1.f / fmaxf(sqrtf(sums[15 + b*3 + 1]), 1e-12f);
  float inv2 = 1.f / fmaxf(sqrtf(sums[15 + b*3 + 2]), 1e-12f);
  float c = fabsf(nx*inn0*vx*inv0 + ny*inn1*vy*inv1 + nz*inn2*vz*inv2);
  float t = block_sum(c, ws);
  if (threadIdx.x == 0) atomicAdd(&sums[2], t);
}

__global__ void final_kernel(const float* __restrict__ sums, float* __restrict__ out) {
  if (threadIdx.x == 0 && blockIdx.x == 0) {
    float esum = 0.f;
#pragma unroll
    for (int i = 0; i < 12; ++i) esum += sums[15 + i];
    float chamfer   = (sums[0] + sums[1]) * (1.f / (float)BN);
    float edge_loss = esum * (1.f / (float)(B * E));
    float ncl       = sums[2] * (1.f / (float)(B * E));
    out[0] = 30000.f * chamfer + 240.f * edge_loss + 200000.f * ncl;
  }
}

} // namespace

extern "C" void kernel_launch(void* const* d_in, const int* in_sizes, int n_in,
                              void* d_out, int out_size, void* d_ws, size_t ws_size,
                              hipStream_t stream) {
  (void)in_sizes; (void)n_in; (void)out_size; (void)ws_size;
  const float* preds   = (const float*)d_in[0];
  const float* gts     = (const float*)d_in[1];
  const float* normals = (const float*)d_in[2];
  const int*   edges   = (const int*)d_in[3];
  char* ws = (char*)d_ws;
  // ws layout: A 512KB | G 512KB | m2 256KB | m1 128KB | nidx 128KB | sums
  float4*             A    = (float4*)(ws);
  float4*             G    = (float4*)(ws + 524288);
  unsigned long long* m2   = (unsigned long long*)(ws + 1048576);
  unsigned*           m1   = (unsigned*)(ws + 1310720);
  unsigned*           nidx = (unsigned*)(ws + 1441792);
  float*              sums = (float*)(ws + 1572864);
  float* out = (float*)d_out;

  prep_kernel<<<dim3(BN/256), 256, 0, stream>>>(preds, gts, A, G, m2, m1, sums);
  // both chamfer passes in one dispatch: z = b + 4*which
  pass_fused<<<dim3(N/CHUNK, N/(256*RT), 2*B), 256, 0, stream>>>(A, G, m2, m1);
  // one wave per row -> BN waves -> BN/4 blocks of 256
  rescan_kernel<<<dim3(BN/4), 256, 0, stream>>>(G, A, m2, nidx);
  reduce_kernel<<<dim3(BN/256), 256, 0, stream>>>(m2, m1, sums);
  edge1_kernel<<<dim3(E/256, B), 256, 0, stream>>>(preds, normals, edges, nidx, sums);
  edge2_kernel<<<dim3(E/256, B), 256, 0, stream>>>(preds, normals, edges, nidx, sums);
  final_kernel<<<1, 64, 0, stream>>>(sums, out);
}